// Round 2
// baseline (772.894 us; speedup 1.0000x reference)
//
#include <hip/hip_runtime.h>
#include <stdint.h>

#define H_DIM 1024
#define E_NUM 8
#define FF_DIM 4096
#define T_TOK 4096   // B*S = 2*2048

typedef __bf16 bf16x8 __attribute__((ext_vector_type(8)));
typedef float f32x4 __attribute__((ext_vector_type(4)));

__device__ __forceinline__ unsigned short f2bf(float f) {
  union { float f; uint32_t u; } v; v.f = f;
  uint32_t u = v.u;
  uint32_t r = u + 0x7fffu + ((u >> 16) & 1u);   // RNE
  return (unsigned short)(r >> 16);
}

// tanh-form GELU: max |err| vs exact-erf gelu ~1e-3 (budget: 5e-2 abs)
__device__ __forceinline__ float gelu_f(float x) {
  float s = x * x;
  float g = x * (1.5957691216f + 0.0713548162f * s);  // 2*0.7978845608*(x+0.044715x^3)
  float t = __expf(-g);
  return x * __builtin_amdgcn_rcpf(1.0f + t);
}

// ---------------- gating ----------------
__global__ __launch_bounds__(64) void gate_kernel(
    const float* __restrict__ x, const float* __restrict__ gw, const float* __restrict__ gb,
    int* __restrict__ topidx, float* __restrict__ topw, int* __restrict__ counts) {
  int t = blockIdx.x;
  int l = threadIdx.x;
  const float* xt = x + (size_t)t * H_DIM;
  float acc[E_NUM];
  #pragma unroll
  for (int e = 0; e < E_NUM; e++) acc[e] = 0.f;
  for (int k = l; k < H_DIM; k += 64) {
    float xv = xt[k];
    #pragma unroll
    for (int e = 0; e < E_NUM; e++) acc[e] += xv * gw[e * H_DIM + k];
  }
  #pragma unroll
  for (int e = 0; e < E_NUM; e++) {
    float v = acc[e];
    #pragma unroll
    for (int off = 32; off > 0; off >>= 1) v += __shfl_xor(v, off, 64);
    acc[e] = v;
  }
  if (l == 0) {
    float s[E_NUM];
    #pragma unroll
    for (int e = 0; e < E_NUM; e++) s[e] = 1.f / (1.f + __expf(-(acc[e] + gb[e])));
    int i1 = 0; float v1 = s[0];
    #pragma unroll
    for (int e = 1; e < E_NUM; e++) if (s[e] > v1) { v1 = s[e]; i1 = e; }
    int i2 = -1; float v2 = -1.f;
    #pragma unroll
    for (int e = 0; e < E_NUM; e++) if (e != i1 && s[e] > v2) { v2 = s[e]; i2 = e; }
    float denom = v1 + v2 + 1e-6f;
    topidx[t * 2]     = i1; topidx[t * 2 + 1] = i2;
    topw[t * 2]       = v1 / denom;
    topw[t * 2 + 1]   = v2 / denom;
    atomicAdd(&counts[i1], 1);
    atomicAdd(&counts[i2], 1);
  }
}

__global__ void init_kernel(int* counts) {
  if (threadIdx.x < E_NUM) counts[threadIdx.x] = 0;
}

__global__ void scan_kernel(const int* __restrict__ counts, int* __restrict__ offs,
                            int* __restrict__ cursor) {
  if (threadIdx.x == 0) {
    int a = 0;
    for (int e = 0; e < E_NUM; e++) { offs[e] = a; a += counts[e]; cursor[e] = 0; }
    offs[E_NUM] = a;                 // == 8192
    offs[E_NUM + 1] = a + T_TOK;     // shared "expert 8" slots 8192..12287
  }
}

__global__ void dispatch_kernel(const int* __restrict__ topidx, const float* __restrict__ topw,
                                const int* __restrict__ offs, int* __restrict__ cursor,
                                int* __restrict__ gidx, int* __restrict__ slot_of) {
  int t = blockIdx.x * blockDim.x + threadIdx.x;
  if (t >= T_TOK) return;
  #pragma unroll
  for (int j = 0; j < 2; j++) {
    int ex  = topidx[t * 2 + j];
    int pos = atomicAdd(&cursor[ex], 1);
    int slot = offs[ex] + pos;
    gidx[slot] = t;
    slot_of[t * 2 + j] = slot;
  }
  gidx[2 * T_TOK + t] = t;   // shared expert gathers token t
}

// ---------------- casts ----------------
__global__ __launch_bounds__(256) void cast_x_kernel(const float* __restrict__ x,
                                                     unsigned short* __restrict__ xb) {
  int i = blockIdx.x * blockDim.x + threadIdx.x;   // covers T*H/4
  float4 v = ((const float4*)x)[i];
  ushort4 o;
  o.x = f2bf(v.x); o.y = f2bf(v.y); o.z = f2bf(v.z); o.w = f2bf(v.w);
  ((ushort4*)xb)[i] = o;
}

// in: [batch][R][C] f32  ->  out: [batch][C][R] bf16
__global__ __launch_bounds__(256) void transpose_cast_kernel(
    const float* __restrict__ in, unsigned short* __restrict__ out, int R, int C) {
  __shared__ float tile[32][33];
  const size_t bo = (size_t)blockIdx.z * (size_t)R * C;
  const float* inb = in + bo;
  unsigned short* outb = out + bo;
  int c0 = blockIdx.x * 32, r0 = blockIdx.y * 32;
  int tx = threadIdx.x & 31, ty = threadIdx.x >> 5;   // 32 x 8
  #pragma unroll
  for (int i = 0; i < 32; i += 8)
    tile[ty + i][tx] = inb[(size_t)(r0 + ty + i) * C + (c0 + tx)];
  __syncthreads();
  #pragma unroll
  for (int i = 0; i < 32; i += 8)
    outb[(size_t)(c0 + ty + i) * R + (r0 + tx)] = f2bf(tile[tx][ty + i]);
}

// ---------------- GEMM 256x256, BK=64, 8 waves (2Mx4N), counted-vmcnt pipeline ----
// LDS rows of 64 bf16 (128B = 8 x 16B units), unit-XOR swizzle u' = u ^ (row&7),
// staged via global_load_lds (linear dest, pre-swizzled global source).
// B columns permuted within each 64-group: LDS row r holds col 4*(r&15)+((r>>4)&3)
//   -> lane l owns 4 adjacent output cols -> coalesced vector stores.
#define BAR() asm volatile("s_barrier" ::: "memory")

template <bool FFN1>
__global__ __launch_bounds__(512, 1) void gemm256(
    const unsigned short* __restrict__ A,    // FFN1: xb [T][1024]; else hdn [12288][4096]
    const unsigned short* __restrict__ Bt,   // wAll [9][N][K] (K-contig)
    const float* __restrict__ b_r,           // routed bias [8][N]
    const float* __restrict__ b_s,           // shared bias [N]
    void* __restrict__ outp,                 // FFN1: bf16 hdn[12288][4096]; else f32 y[12288][1024]
    const int* __restrict__ gidx,
    const int* __restrict__ offs,            // [10]
    int K, int N) {
  __shared__ __align__(16) unsigned short ldsA[2][256 * 64];
  __shared__ __align__(16) unsigned short ldsB[2][256 * 64];
  __shared__ int tokLds[256];

  const int tid = threadIdx.x;
  const int e  = blockIdx.z;
  const int o0 = offs[e], o1 = offs[e + 1];
  const int cnt = o1 - o0;
  const int m0 = blockIdx.y * 256;
  if (m0 >= cnt) return;
  const int base  = o0 + m0;
  const int valid = min(256, cnt - m0);
  const int n0 = blockIdx.x * 256;

  if (FFN1) {
    if (tid < 256) tokLds[tid] = gidx[base + min(tid, valid - 1)];
    __syncthreads();
  }

  // ---- staging setup: 512 threads x 4 chunks x 16B per operand per K-tile ----
  const int rlo  = tid >> 3;                     // 0..63
  const int uSrc = (tid & 7) ^ (rlo & 7);        // pre-swizzled source unit
  const unsigned short* aPtr[4];
  const unsigned short* bPtr[4];
  int dstE[4];
  const unsigned short* BtE = Bt + (size_t)e * (size_t)N * (size_t)K;
  #pragma unroll
  for (int j = 0; j < 4; j++) {
    int r = j * 64 + rlo;                        // staging row 0..255
    size_t arow = FFN1 ? (size_t)tokLds[r] : (size_t)(base + r);
    aPtr[j] = A + arow * (size_t)K + uSrc * 8;
    int nr = n0 + (r & 192) + ((r & 15) << 2) + ((r >> 4) & 3);  // col permutation
    bPtr[j] = BtE + (size_t)nr * (size_t)K + uSrc * 8;
    dstE[j] = (j * 512 + tid) * 8;               // ushort index (16B chunks)
  }

#define STAGE(c, kt)                                                              \
  {                                                                               \
    _Pragma("unroll")                                                             \
    for (int j = 0; j < 4; j++) {                                                 \
      __builtin_amdgcn_global_load_lds(                                           \
          (const __attribute__((address_space(1))) void*)(aPtr[j] + (kt) * 64),   \
          (__attribute__((address_space(3))) void*)(&ldsA[c][dstE[j]]), 16, 0, 0);\
      __builtin_amdgcn_global_load_lds(                                           \
          (const __attribute__((address_space(1))) void*)(bPtr[j] + (kt) * 64),   \
          (__attribute__((address_space(3))) void*)(&ldsB[c][dstE[j]]), 16, 0, 0);\
    }                                                                             \
  }

  const int lane = tid & 63;
  const int w = tid >> 6;                 // 0..7
  const int wr = w >> 2, wc = w & 3;      // 2M x 4N waves, per-wave 128x64
  const int l15 = lane & 15, l4 = lane >> 4, l7 = lane & 7;

  f32x4 acc[8][4];
  #pragma unroll
  for (int m = 0; m < 8; m++)
    #pragma unroll
    for (int n = 0; n < 4; n++) acc[m][n] = (f32x4){0.f, 0.f, 0.f, 0.f};

  const int nt = K >> 6;

  // prologue: tiles 0,1 in flight; wait tile 0
  STAGE(0, 0);
  STAGE(1, 1);
  asm volatile("s_waitcnt vmcnt(8)" ::: "memory");
  BAR();

  for (int t = 0; t < nt; t++) {
    const int c = t & 1;
    const char* pA = (const char*)&ldsA[c][0];
    const char* pB = (const char*)&ldsB[c][0];
    bf16x8 aq[4][2], bq[4][2];

    // phase 1: read A[0..3], B[0..1]; MFMA quadrant (0..3, 0..1)
    #pragma unroll
    for (int m = 0; m < 4; m++)
      #pragma unroll
      for (int kk = 0; kk < 2; kk++)
        aq[m][kk] = *(const bf16x8*)(pA + (wr * 128 + m * 16 + l15) * 128 + (((kk * 4 + l4) ^ l7) * 16));
    #pragma unroll
    for (int n = 0; n < 2; n++)
      #pragma unroll
      for (int kk = 0; kk < 2; kk++)
        bq[n][kk] = *(const bf16x8*)(pB + (wc * 64 + n * 16 + l15) * 128 + (((kk * 4 + l4) ^ l7) * 16));
    BAR();
    __builtin_amdgcn_s_setprio(1);
    #pragma unroll
    for (int m = 0; m < 4; m++)
      #pragma unroll
      for (int n = 0; n < 2; n++)
        #pragma unroll
        for (int kk = 0; kk < 2; kk++)
          acc[m][n] = __builtin_amdgcn_mfma_f32_16x16x32_bf16(aq[m][kk], bq[n][kk], acc[m][n], 0, 0, 0);
    __builtin_amdgcn_s_setprio(0);
    BAR();

    // phase 2: read B[2..3]; MFMA (0..3, 2..3)
    #pragma unroll
    for (int n = 2; n < 4; n++)
      #pragma unroll
      for (int kk = 0; kk < 2; kk++)
        bq[n][kk] = *(const bf16x8*)(pB + (wc * 64 + n * 16 + l15) * 128 + (((kk * 4 + l4) ^ l7) * 16));
    BAR();
    __builtin_amdgcn_s_setprio(1);
    #pragma unroll
    for (int m = 0; m < 4; m++)
      #pragma unroll
      for (int n = 2; n < 4; n++)
        #pragma unroll
        for (int kk = 0; kk < 2; kk++)
          acc[m][n] = __builtin_amdgcn_mfma_f32_16x16x32_bf16(aq[m][kk], bq[n][kk], acc[m][n], 0, 0, 0);
    __builtin_amdgcn_s_setprio(0);
    BAR();

    // phase 3: read A[4..7]; MFMA (4..7, 0..1)
    #pragma unroll
    for (int m = 0; m < 4; m++)
      #pragma unroll
      for (int kk = 0; kk < 2; kk++)
        aq[m][kk] = *(const bf16x8*)(pA + (wr * 128 + (4 + m) * 16 + l15) * 128 + (((kk * 4 + l4) ^ l7) * 16));
    BAR();
    __builtin_amdgcn_s_setprio(1);
    #pragma unroll
    for (int m = 0; m < 4; m++)
      #pragma unroll
      for (int n = 0; n < 2; n++)
        #pragma unroll
        for (int kk = 0; kk < 2; kk++)
          acc[4 + m][n] = __builtin_amdgcn_mfma_f32_16x16x32_bf16(aq[m][kk], bq[n][kk], acc[4 + m][n], 0, 0, 0);
    __builtin_amdgcn_s_setprio(0);
    BAR();

    // phase 4: MFMA (4..7, 2..3)
    __builtin_amdgcn_s_setprio(1);
    #pragma unroll
    for (int m = 0; m < 4; m++)
      #pragma unroll
      for (int n = 2; n < 4; n++)
        #pragma unroll
        for (int kk = 0; kk < 2; kk++)
          acc[4 + m][n] = __builtin_amdgcn_mfma_f32_16x16x32_bf16(aq[m][kk], bq[n][kk], acc[4 + m][n], 0, 0, 0);
    __builtin_amdgcn_s_setprio(0);
    BAR();   // all waves done reading buf c

    // boundary: stage tile t+2 into buf c; keep 8 loads in flight across the wait
    if (t + 2 < nt) {
      STAGE(c, t + 2);
      asm volatile("s_waitcnt vmcnt(8)" ::: "memory");   // tile t+1 landed
    } else {
      asm volatile("s_waitcnt vmcnt(0)" ::: "memory");
    }
    BAR();
  }
#undef STAGE

  // ---- epilogue: lane l owns cols c0..c0+3 (B-permutation) ----
  const float* bias = (e < E_NUM) ? (b_r + (size_t)e * N) : b_s;
  const int c0 = n0 + wc * 64 + 4 * l15;
  float4 bv = *(const float4*)(bias + c0);
  if (FFN1) {
    unsigned short* hdn = (unsigned short*)outp;
    #pragma unroll
    for (int fm = 0; fm < 8; fm++) {
      #pragma unroll
      for (int j = 0; j < 4; j++) {
        int rl = wr * 128 + fm * 16 + l4 * 4 + j;
        if (rl < valid) {
          ushort4 o;
          o.x = f2bf(gelu_f(acc[fm][0][j] + bv.x));
          o.y = f2bf(gelu_f(acc[fm][1][j] + bv.y));
          o.z = f2bf(gelu_f(acc[fm][2][j] + bv.z));
          o.w = f2bf(gelu_f(acc[fm][3][j] + bv.w));
          *(ushort4*)(hdn + (size_t)(base + rl) * N + c0) = o;
        }
      }
    }
  } else {
    float* y = (float*)outp;
    #pragma unroll
    for (int fm = 0; fm < 8; fm++) {
      #pragma unroll
      for (int j = 0; j < 4; j++) {
        int rl = wr * 128 + fm * 16 + l4 * 4 + j;
        if (rl < valid) {
          float4 o;
          o.x = acc[fm][0][j] + bv.x;
          o.y = acc[fm][1][j] + bv.y;
          o.z = acc[fm][2][j] + bv.z;
          o.w = acc[fm][3][j] + bv.w;
          *(float4*)(y + (size_t)(base + rl) * N + c0) = o;
        }
      }
    }
  }
}

// out[t] = w1*y[s1] + w2*y[s2] + 0.1*y[8192+t]   (biases already in y)
__global__ __launch_bounds__(256) void combine_kernel(
    const float* __restrict__ y, const float* __restrict__ topw,
    const int* __restrict__ slot_of, float* __restrict__ out) {
  int t = blockIdx.x;
  int g = threadIdx.x;
  int s1 = slot_of[2 * t], s2 = slot_of[2 * t + 1];
  float w1 = topw[2 * t], w2 = topw[2 * t + 1];
  float4 a = *(const float4*)(y + (size_t)s1 * H_DIM + g * 4);
  float4 b = *(const float4*)(y + (size_t)s2 * H_DIM + g * 4);
  float4 c = *(const float4*)(y + (size_t)(2 * T_TOK + t) * H_DIM + g * 4);
  float4 o;
  o.x = w1 * a.x + w2 * b.x + 0.1f * c.x;
  o.y = w1 * a.y + w2 * b.y + 0.1f * c.y;
  o.z = w1 * a.z + w2 * b.z + 0.1f * c.z;
  o.w = w1 * a.w + w2 * b.w + 0.1f * c.w;
  *(float4*)(out + (size_t)t * H_DIM + g * 4) = o;
}

// ---------------- host ----------------
extern "C" void kernel_launch(void* const* d_in, const int* in_sizes, int n_in,
                              void* d_out, int out_size, void* d_ws, size_t ws_size,
                              hipStream_t stream) {
  const float* x   = (const float*)d_in[0];
  const float* gw  = (const float*)d_in[1];
  const float* gb  = (const float*)d_in[2];
  const float* w1  = (const float*)d_in[3];
  const float* b1  = (const float*)d_in[4];
  const float* w2  = (const float*)d_in[5];
  const float* b2  = (const float*)d_in[6];
  const float* sw1 = (const float*)d_in[7];
  const float* sb1 = (const float*)d_in[8];
  const float* sw2 = (const float*)d_in[9];
  const float* sb2 = (const float*)d_in[10];
  float* out = (float*)d_out;

  char* p = (char*)d_ws;
  auto alloc = [&](size_t bytes) {
    char* r = p;
    p += (bytes + 255) & ~(size_t)255;
    return r;
  };
  int*   counts  = (int*)alloc(E_NUM * 4);
  int*   cursor  = (int*)alloc(E_NUM * 4);
  int*   offs    = (int*)alloc((E_NUM + 2) * 4);
  int*   topidx  = (int*)alloc((size_t)T_TOK * 2 * 4);
  float* topw    = (float*)alloc((size_t)T_TOK * 2 * 4);
  int*   slot_of = (int*)alloc((size_t)T_TOK * 2 * 4);
  int*   gidx    = (int*)alloc((size_t)3 * T_TOK * 4);
  unsigned short* xb   = (unsigned short*)alloc((size_t)T_TOK * H_DIM * 2);
  unsigned short* wAll = (unsigned short*)alloc((size_t)(E_NUM + 1) * FF_DIM * H_DIM * 2);
  unsigned short* hdn  = (unsigned short*)alloc((size_t)3 * T_TOK * FF_DIM * 2);   // 12288 x 4096 bf16
  float*          yb   = (float*)alloc((size_t)3 * T_TOK * H_DIM * 4);             // 12288 x 1024 f32

  // routing
  init_kernel<<<1, 64, 0, stream>>>(counts);
  gate_kernel<<<T_TOK, 64, 0, stream>>>(x, gw, gb, topidx, topw, counts);
  scan_kernel<<<1, 1, 0, stream>>>(counts, offs, cursor);
  dispatch_kernel<<<T_TOK / 256, 256, 0, stream>>>(topidx, topw, offs, cursor, gidx, slot_of);

  // x -> bf16
  cast_x_kernel<<<(T_TOK * H_DIM / 4) / 256, 256, 0, stream>>>(x, xb);

  // FFN1 weights -> bf16 [N][K]; shared expert = expert 8
  transpose_cast_kernel<<<dim3(FF_DIM / 32, H_DIM / 32, E_NUM), 256, 0, stream>>>(w1, wAll, H_DIM, FF_DIM);
  transpose_cast_kernel<<<dim3(FF_DIM / 32, H_DIM / 32, 1), 256, 0, stream>>>(
      sw1, wAll + (size_t)E_NUM * FF_DIM * H_DIM, H_DIM, FF_DIM);
  gemm256<true><<<dim3(FF_DIM / 256, 16, E_NUM + 1), 512, 0, stream>>>(
      xb, wAll, b1, sb1, hdn, gidx, offs, H_DIM, FF_DIM);

  // FFN2 weights (reuse wAll) -> bf16 [N][K]
  transpose_cast_kernel<<<dim3(H_DIM / 32, FF_DIM / 32, E_NUM), 256, 0, stream>>>(w2, wAll, FF_DIM, H_DIM);
  transpose_cast_kernel<<<dim3(H_DIM / 32, FF_DIM / 32, 1), 256, 0, stream>>>(
      sw2, wAll + (size_t)E_NUM * FF_DIM * H_DIM, FF_DIM, H_DIM);
  gemm256<false><<<dim3(H_DIM / 256, 16, E_NUM + 1), 512, 0, stream>>>(
      hdn, wAll, b2, sb2, yb, gidx, offs, FF_DIM, H_DIM);

  // weighted combine (routed top-2 + 0.1 * shared)
  combine_kernel<<<T_TOK, 256, 0, stream>>>(yb, topw, slot_of, out);
}

// Round 3
// 692.864 us; speedup vs baseline: 1.1155x; 1.1155x over previous
//
#include <hip/hip_runtime.h>
#include <stdint.h>

#define H_DIM 1024
#define E_NUM 8
#define FF_DIM 4096
#define T_TOK 4096   // B*S = 2*2048

typedef __bf16 bf16x8 __attribute__((ext_vector_type(8)));
typedef float f32x4 __attribute__((ext_vector_type(4)));

#define AS1 __attribute__((address_space(1)))
#define AS3 __attribute__((address_space(3)))

__device__ __forceinline__ unsigned short f2bf(float f) {
  union { float f; uint32_t u; } v; v.f = f;
  uint32_t u = v.u;
  uint32_t r = u + 0x7fffu + ((u >> 16) & 1u);   // RNE
  return (unsigned short)(r >> 16);
}

// tanh-form GELU: max |err| vs exact-erf gelu ~1e-3 (budget: 5e-2 abs)
__device__ __forceinline__ float gelu_f(float x) {
  float s = x * x;
  float g = x * (1.5957691216f + 0.0713548162f * s);
  float t = __expf(-g);
  return x * __builtin_amdgcn_rcpf(1.0f + t);
}

// ---------------- gating ----------------
__global__ __launch_bounds__(64) void gate_kernel(
    const float* __restrict__ x, const float* __restrict__ gw, const float* __restrict__ gb,
    int* __restrict__ topidx, float* __restrict__ topw, int* __restrict__ counts) {
  int t = blockIdx.x;
  int l = threadIdx.x;
  const float* xt = x + (size_t)t * H_DIM;
  float acc[E_NUM];
  #pragma unroll
  for (int e = 0; e < E_NUM; e++) acc[e] = 0.f;
  for (int k = l; k < H_DIM; k += 64) {
    float xv = xt[k];
    #pragma unroll
    for (int e = 0; e < E_NUM; e++) acc[e] += xv * gw[e * H_DIM + k];
  }
  #pragma unroll
  for (int e = 0; e < E_NUM; e++) {
    float v = acc[e];
    #pragma unroll
    for (int off = 32; off > 0; off >>= 1) v += __shfl_xor(v, off, 64);
    acc[e] = v;
  }
  if (l == 0) {
    float s[E_NUM];
    #pragma unroll
    for (int e = 0; e < E_NUM; e++) s[e] = 1.f / (1.f + __expf(-(acc[e] + gb[e])));
    int i1 = 0; float v1 = s[0];
    #pragma unroll
    for (int e = 1; e < E_NUM; e++) if (s[e] > v1) { v1 = s[e]; i1 = e; }
    int i2 = -1; float v2 = -1.f;
    #pragma unroll
    for (int e = 0; e < E_NUM; e++) if (e != i1 && s[e] > v2) { v2 = s[e]; i2 = e; }
    float denom = v1 + v2 + 1e-6f;
    topidx[t * 2]     = i1; topidx[t * 2 + 1] = i2;
    topw[t * 2]       = v1 / denom;
    topw[t * 2 + 1]   = v2 / denom;
    atomicAdd(&counts[i1], 1);
    atomicAdd(&counts[i2], 1);
  }
}

__global__ void init_kernel(int* counts) {
  if (threadIdx.x < E_NUM) counts[threadIdx.x] = 0;
}

__global__ void scan_kernel(const int* __restrict__ counts, int* __restrict__ offs,
                            int* __restrict__ cursor) {
  if (threadIdx.x == 0) {
    int a = 0;
    for (int e = 0; e < E_NUM; e++) { offs[e] = a; a += counts[e]; cursor[e] = 0; }
    offs[E_NUM] = a;                 // == 8192
    offs[E_NUM + 1] = a + T_TOK;     // shared "expert 8" slots 8192..12287
  }
}

__global__ void dispatch_kernel(const int* __restrict__ topidx, const float* __restrict__ topw,
                                const int* __restrict__ offs, int* __restrict__ cursor,
                                int* __restrict__ gidx, int* __restrict__ slot_of) {
  int t = blockIdx.x * blockDim.x + threadIdx.x;
  if (t >= T_TOK) return;
  #pragma unroll
  for (int j = 0; j < 2; j++) {
    int ex  = topidx[t * 2 + j];
    int pos = atomicAdd(&cursor[ex], 1);
    int slot = offs[ex] + pos;
    gidx[slot] = t;
    slot_of[t * 2 + j] = slot;
  }
  gidx[2 * T_TOK + t] = t;   // shared expert gathers token t
}

// ---------------- casts ----------------
__global__ __launch_bounds__(256) void cast_x_kernel(const float* __restrict__ x,
                                                     unsigned short* __restrict__ xb) {
  int i = blockIdx.x * blockDim.x + threadIdx.x;   // covers T*H/4
  float4 v = ((const float4*)x)[i];
  ushort4 o;
  o.x = f2bf(v.x); o.y = f2bf(v.y); o.z = f2bf(v.z); o.w = f2bf(v.w);
  ((ushort4*)xb)[i] = o;
}

// in: [batch][R][C] f32  ->  out: [batch][C][R] bf16
__global__ __launch_bounds__(256) void transpose_cast_kernel(
    const float* __restrict__ in, unsigned short* __restrict__ out, int R, int C) {
  __shared__ float tile[32][33];
  const size_t bo = (size_t)blockIdx.z * (size_t)R * C;
  const float* inb = in + bo;
  unsigned short* outb = out + bo;
  int c0 = blockIdx.x * 32, r0 = blockIdx.y * 32;
  int tx = threadIdx.x & 31, ty = threadIdx.x >> 5;   // 32 x 8
  #pragma unroll
  for (int i = 0; i < 32; i += 8)
    tile[ty + i][tx] = inb[(size_t)(r0 + ty + i) * C + (c0 + tx)];
  __syncthreads();
  #pragma unroll
  for (int i = 0; i < 32; i += 8)
    outb[(size_t)(c0 + ty + i) * R + (r0 + tx)] = f2bf(tile[tx][ty + i]);
}

// ---------------- GEMM 256x256, BK=64, 8 waves (2Mx4N), m201-style 8-phase ----
// LDS: per operand 2 tile-buffers (buf0=even K-tiles, buf1=odd) x 2 halves
// (128 rows x 64 bf16 each). Rows of 128B = 8 x 16B units, XOR swizzle
// u' = u ^ (row&7); staged via global_load_lds (linear dest, pre-swizzled src).
// B columns permuted within each 64-group: LDS row r holds col 4*(r&15)+((r>>4)&3)
//   -> lane owns 4 adjacent output cols -> coalesced vector stores.
// Schedule per iter (2 K-tiles t0=2i in buf0, t1=2i+1 in buf1):
//  ph1: rdA(b0,m0-3)+rdB(b0,n0-1)[12]; stgA(b1,h0,t1); BAR; Q00; BAR
//  ph2: rdB(b0,n2-3)[4];               stgA(b1,h1,t1); BAR; Q01; BAR
//  ph3: rdA(b0,m4-7)[8];               stgB(b0,h0,t2); BAR; Q11; BAR
//  ph4:                                stgB(b0,h1,t2); vmcnt(4); BAR; Q10; BAR
//  ph5-8: same on buf1, staging A(b0,t2), B(b1,t3).
// vmcnt(4) at ph4 retires exactly tile t1's 4 halves (prev ph7,8 + ph1,2);
// at ph8 retires tile t2's 4 halves (ph3,4,5,6). Never drains to 0 mid-loop.
template <bool FFN1>
__global__ __launch_bounds__(512, 1) void gemm8p(
    const unsigned short* __restrict__ A,    // FFN1: xb [T][1024]; else hdn [12288][4096]
    const unsigned short* __restrict__ Bt,   // wAll [9][N][K] (K-contig)
    const float* __restrict__ b_r,           // routed bias [8][N]
    const float* __restrict__ b_s,           // shared bias [N]
    void* __restrict__ outp,                 // FFN1: bf16 hdn; else f32 y
    const int* __restrict__ gidx,
    const int* __restrict__ offs,            // [10]
    int K, int N) {
  __shared__ __align__(16) unsigned short ldsA[2][2][128 * 64];
  __shared__ __align__(16) unsigned short ldsB[2][2][128 * 64];
  __shared__ int tokLds[256];

  const int tid = threadIdx.x;
  const int e  = blockIdx.z;
  const int o0 = offs[e], o1 = offs[e + 1];
  const int cnt = o1 - o0;
  const int m0 = blockIdx.y * 256;
  if (m0 >= cnt) return;
  const int base  = o0 + m0;
  const int valid = min(256, cnt - m0);
  const int n0 = blockIdx.x * 256;

  if (FFN1) {
    if (tid < 256) tokLds[tid] = gidx[base + min(tid, valid - 1)];
    __syncthreads();
  }

  // ---- staging pointers: thread covers rows {0,64,128,192}+(tid>>3), unit pre-swizzled
  const int rlo  = tid >> 3;                     // 0..63
  const int uSrc = (tid & 7) ^ (rlo & 7);        // source 16B-unit (inverse swizzle)
  const unsigned short* aPtr[4];
  const unsigned short* bPtr[4];
  const unsigned short* BtE = Bt + (size_t)e * (size_t)N * (size_t)K;
  #pragma unroll
  for (int j = 0; j < 4; j++) {
    int r = j * 64 + rlo;                        // tile row 0..255
    size_t arow = FFN1 ? (size_t)tokLds[r] : (size_t)(base + r);
    aPtr[j] = A + arow * (size_t)K + uSrc * 8;
    int nr = n0 + (r & 192) + ((r & 15) << 2) + ((r >> 4) & 3);  // col permutation
    bPtr[j] = BtE + (size_t)nr * (size_t)K + uSrc * 8;
  }

  // per-half dest: chunk (j&1)*512+tid -> ushort offset *8
#define STG_A(BUF, HJ, KT)                                                          \
  __builtin_amdgcn_global_load_lds(                                                 \
      (const AS1 void*)(aPtr[HJ] + (size_t)(KT) * 64),                              \
      (AS3 void*)(&ldsA[BUF][(HJ) >> 1][tid * 8]), 16, 0, 0);                       \
  __builtin_amdgcn_global_load_lds(                                                 \
      (const AS1 void*)(aPtr[(HJ) + 1] + (size_t)(KT) * 64),                        \
      (AS3 void*)(&ldsA[BUF][(HJ) >> 1][(512 + tid) * 8]), 16, 0, 0);
#define STG_B(BUF, HJ, KT)                                                          \
  __builtin_amdgcn_global_load_lds(                                                 \
      (const AS1 void*)(bPtr[HJ] + (size_t)(KT) * 64),                              \
      (AS3 void*)(&ldsB[BUF][(HJ) >> 1][tid * 8]), 16, 0, 0);                       \
  __builtin_amdgcn_global_load_lds(                                                 \
      (const AS1 void*)(bPtr[(HJ) + 1] + (size_t)(KT) * 64),                        \
      (AS3 void*)(&ldsB[BUF][(HJ) >> 1][(512 + tid) * 8]), 16, 0, 0);

  const int lane = tid & 63;
  const int w = tid >> 6;                 // 0..7
  const int wr = w >> 2, wc = w & 3;      // 2M x 4N waves, per-wave 128x64
  const int l15 = lane & 15, l4 = lane >> 4, l7 = lane & 7;
  const int bRow = (wc & 1) * 64;

  const char* pA0 = (const char*)&ldsA[0][wr][0];
  const char* pA1 = (const char*)&ldsA[1][wr][0];
  const char* pB0 = (const char*)&ldsB[0][wc >> 1][0];
  const char* pB1 = (const char*)&ldsB[1][wc >> 1][0];

  bf16x8 aq[4][2], bq[4][2];
  f32x4 acc[8][4];
  #pragma unroll
  for (int m = 0; m < 8; m++)
    #pragma unroll
    for (int n = 0; n < 4; n++) acc[m][n] = (f32x4){0.f, 0.f, 0.f, 0.f};

#define READ_A(P, FM0)                                                              \
  _Pragma("unroll")                                                                 \
  for (int m = 0; m < 4; m++)                                                       \
    _Pragma("unroll")                                                               \
    for (int kk = 0; kk < 2; kk++)                                                  \
      aq[m][kk] = *(const bf16x8*)((P) + (((FM0) + m) * 16 + l15) * 128 +           \
                                   (((kk * 4 + l4) ^ l7) << 4));
#define READ_B(P, F0)                                                               \
  _Pragma("unroll")                                                                 \
  for (int f = (F0); f < (F0) + 2; f++)                                             \
    _Pragma("unroll")                                                               \
    for (int kk = 0; kk < 2; kk++)                                                  \
      bq[f][kk] = *(const bf16x8*)((P) + (bRow + f * 16 + l15) * 128 +              \
                                   (((kk * 4 + l4) ^ l7) << 4));
#define MFMA_Q(MB, NB)                                                              \
  __builtin_amdgcn_s_setprio(1);                                                    \
  _Pragma("unroll")                                                                 \
  for (int m = 0; m < 4; m++)                                                       \
    _Pragma("unroll")                                                               \
    for (int n = 0; n < 2; n++)                                                     \
      _Pragma("unroll")                                                             \
      for (int kk = 0; kk < 2; kk++)                                                \
        acc[(MB) + m][(NB) + n] = __builtin_amdgcn_mfma_f32_16x16x32_bf16(          \
            aq[m][kk], bq[(NB) + n][kk], acc[(MB) + m][(NB) + n], 0, 0, 0);         \
  __builtin_amdgcn_s_setprio(0);
#define BAR() __builtin_amdgcn_s_barrier()
#define WAITV4() asm volatile("s_waitcnt vmcnt(4)" ::: "memory")

  const int nt = K >> 6;          // K-tiles (even: 16 or 64)
  const int ntm1 = nt - 1;
  const int nIter = nt >> 1;

  // prologue: tile0 -> buf0 (8 loads), B(tile1) -> buf1 (4 loads); wait tile0.
  STG_A(0, 0, 0); STG_A(0, 2, 0);
  STG_B(0, 0, 0); STG_B(0, 2, 0);
  STG_B(1, 0, 1); STG_B(1, 2, 1);
  WAITV4();
  BAR();

  for (int i = 0; i < nIter; i++) {
    const int t1 = 2 * i + 1;
    const int t2 = min(2 * i + 2, ntm1);
    const int t3 = min(2 * i + 3, ntm1);
    // ph1
    READ_A(pA0, 0); READ_B(pB0, 0);
    STG_A(1, 0, t1);
    BAR(); MFMA_Q(0, 0); BAR();
    // ph2
    READ_B(pB0, 2);
    STG_A(1, 2, t1);
    BAR(); MFMA_Q(0, 2); BAR();
    // ph3
    READ_A(pA0, 4);
    STG_B(0, 0, t2);
    BAR(); MFMA_Q(4, 2); BAR();
    // ph4
    STG_B(0, 2, t2);
    WAITV4();
    BAR(); MFMA_Q(4, 0); BAR();
    // ph5
    READ_A(pA1, 0); READ_B(pB1, 0);
    STG_A(0, 0, t2);
    BAR(); MFMA_Q(0, 0); BAR();
    // ph6
    READ_B(pB1, 2);
    STG_A(0, 2, t2);
    BAR(); MFMA_Q(0, 2); BAR();
    // ph7
    READ_A(pA1, 4);
    STG_B(1, 0, t3);
    BAR(); MFMA_Q(4, 2); BAR();
    // ph8
    STG_B(1, 2, t3);
    WAITV4();
    BAR(); MFMA_Q(4, 0); BAR();
  }
#undef STG_A
#undef STG_B
#undef READ_A
#undef READ_B
#undef MFMA_Q

  // ---- epilogue: lane owns cols c0..c0+3 (B-permutation) ----
  const float* bias = (e < E_NUM) ? (b_r + (size_t)e * N) : b_s;
  const int c0 = n0 + wc * 64 + 4 * l15;
  float4 bv = *(const float4*)(bias + c0);
  if (FFN1) {
    unsigned short* hdn = (unsigned short*)outp;
    #pragma unroll
    for (int fm = 0; fm < 8; fm++) {
      #pragma unroll
      for (int j = 0; j < 4; j++) {
        int rl = wr * 128 + fm * 16 + l4 * 4 + j;
        if (rl < valid) {
          ushort4 o;
          o.x = f2bf(gelu_f(acc[fm][0][j] + bv.x));
          o.y = f2bf(gelu_f(acc[fm][1][j] + bv.y));
          o.z = f2bf(gelu_f(acc[fm][2][j] + bv.z));
          o.w = f2bf(gelu_f(acc[fm][3][j] + bv.w));
          *(ushort4*)(hdn + (size_t)(base + rl) * N + c0) = o;
        }
      }
    }
  } else {
    float* y = (float*)outp;
    #pragma unroll
    for (int fm = 0; fm < 8; fm++) {
      #pragma unroll
      for (int j = 0; j < 4; j++) {
        int rl = wr * 128 + fm * 16 + l4 * 4 + j;
        if (rl < valid) {
          float4 o;
          o.x = acc[fm][0][j] + bv.x;
          o.y = acc[fm][1][j] + bv.y;
          o.z = acc[fm][2][j] + bv.z;
          o.w = acc[fm][3][j] + bv.w;
          *(float4*)(y + (size_t)(base + rl) * N + c0) = o;
        }
      }
    }
  }
}

// out[t] = w1*y[s1] + w2*y[s2] + 0.1*y[8192+t]   (biases already in y)
__global__ __launch_bounds__(256) void combine_kernel(
    const float* __restrict__ y, const float* __restrict__ topw,
    const int* __restrict__ slot_of, float* __restrict__ out) {
  int t = blockIdx.x;
  int g = threadIdx.x;
  int s1 = slot_of[2 * t], s2 = slot_of[2 * t + 1];
  float w1 = topw[2 * t], w2 = topw[2 * t + 1];
  float4 a = *(const float4*)(y + (size_t)s1 * H_DIM + g * 4);
  float4 b = *(const float4*)(y + (size_t)s2 * H_DIM + g * 4);
  float4 c = *(const float4*)(y + (size_t)(2 * T_TOK + t) * H_DIM + g * 4);
  float4 o;
  o.x = w1 * a.x + w2 * b.x + 0.1f * c.x;
  o.y = w1 * a.y + w2 * b.y + 0.1f * c.y;
  o.z = w1 * a.z + w2 * b.z + 0.1f * c.z;
  o.w = w1 * a.w + w2 * b.w + 0.1f * c.w;
  *(float4*)(out + (size_t)t * H_DIM + g * 4) = o;
}

// ---------------- host ----------------
extern "C" void kernel_launch(void* const* d_in, const int* in_sizes, int n_in,
                              void* d_out, int out_size, void* d_ws, size_t ws_size,
                              hipStream_t stream) {
  const float* x   = (const float*)d_in[0];
  const float* gw  = (const float*)d_in[1];
  const float* gb  = (const float*)d_in[2];
  const float* w1  = (const float*)d_in[3];
  const float* b1  = (const float*)d_in[4];
  const float* w2  = (const float*)d_in[5];
  const float* b2  = (const float*)d_in[6];
  const float* sw1 = (const float*)d_in[7];
  const float* sb1 = (const float*)d_in[8];
  const float* sw2 = (const float*)d_in[9];
  const float* sb2 = (const float*)d_in[10];
  float* out = (float*)d_out;

  char* p = (char*)d_ws;
  auto alloc = [&](size_t bytes) {
    char* r = p;
    p += (bytes + 255) & ~(size_t)255;
    return r;
  };
  int*   counts  = (int*)alloc(E_NUM * 4);
  int*   cursor  = (int*)alloc(E_NUM * 4);
  int*   offs    = (int*)alloc((E_NUM + 2) * 4);
  int*   topidx  = (int*)alloc((size_t)T_TOK * 2 * 4);
  float* topw    = (float*)alloc((size_t)T_TOK * 2 * 4);
  int*   slot_of = (int*)alloc((size_t)T_TOK * 2 * 4);
  int*   gidx    = (int*)alloc((size_t)3 * T_TOK * 4);
  unsigned short* xb   = (unsigned short*)alloc((size_t)T_TOK * H_DIM * 2);
  unsigned short* wAll = (unsigned short*)alloc((size_t)(E_NUM + 1) * FF_DIM * H_DIM * 2);
  unsigned short* hdn  = (unsigned short*)alloc((size_t)3 * T_TOK * FF_DIM * 2);   // 12288 x 4096 bf16
  float*          yb   = (float*)alloc((size_t)3 * T_TOK * H_DIM * 4);             // 12288 x 1024 f32

  // routing
  init_kernel<<<1, 64, 0, stream>>>(counts);
  gate_kernel<<<T_TOK, 64, 0, stream>>>(x, gw, gb, topidx, topw, counts);
  scan_kernel<<<1, 1, 0, stream>>>(counts, offs, cursor);
  dispatch_kernel<<<T_TOK / 256, 256, 0, stream>>>(topidx, topw, offs, cursor, gidx, slot_of);

  // x -> bf16
  cast_x_kernel<<<(T_TOK * H_DIM / 4) / 256, 256, 0, stream>>>(x, xb);

  // FFN1 weights -> bf16 [N][K]; shared expert = expert 8
  transpose_cast_kernel<<<dim3(FF_DIM / 32, H_DIM / 32, E_NUM), 256, 0, stream>>>(w1, wAll, H_DIM, FF_DIM);
  transpose_cast_kernel<<<dim3(FF_DIM / 32, H_DIM / 32, 1), 256, 0, stream>>>(
      sw1, wAll + (size_t)E_NUM * FF_DIM * H_DIM, H_DIM, FF_DIM);
  gemm8p<true><<<dim3(FF_DIM / 256, 16, E_NUM + 1), 512, 0, stream>>>(
      xb, wAll, b1, sb1, hdn, gidx, offs, H_DIM, FF_DIM);

  // FFN2 weights (reuse wAll) -> bf16 [N][K]
  transpose_cast_kernel<<<dim3(H_DIM / 32, FF_DIM / 32, E_NUM), 256, 0, stream>>>(w2, wAll, FF_DIM, H_DIM);
  transpose_cast_kernel<<<dim3(H_DIM / 32, FF_DIM / 32, 1), 256, 0, stream>>>(
      sw2, wAll + (size_t)E_NUM * FF_DIM * H_DIM, FF_DIM, H_DIM);
  gemm8p<false><<<dim3(H_DIM / 256, 16, E_NUM + 1), 512, 0, stream>>>(
      hdn, wAll, b2, sb2, yb, gidx, offs, FF_DIM, H_DIM);

  // weighted combine (routed top-2 + 0.1 * shared)
  combine_kernel<<<T_TOK, 256, 0, stream>>>(yb, topw, slot_of, out);
}

// Round 4
// 591.068 us; speedup vs baseline: 1.3076x; 1.1722x over previous
//
#include <hip/hip_runtime.h>
#include <stdint.h>

#define H_DIM 1024
#define E_NUM 8
#define FF_DIM 4096
#define T_TOK 4096   // B*S = 2*2048
#define MAX_MT 104   // max 128-row tiles: routed <=72, shared 32

typedef __bf16 bf16x8 __attribute__((ext_vector_type(8)));
typedef float f32x4 __attribute__((ext_vector_type(4)));

#define AS1 __attribute__((address_space(1)))
#define AS3 __attribute__((address_space(3)))

__device__ __forceinline__ unsigned short f2bf(float f) {
  union { float f; uint32_t u; } v; v.f = f;
  uint32_t u = v.u;
  uint32_t r = u + 0x7fffu + ((u >> 16) & 1u);   // RNE
  return (unsigned short)(r >> 16);
}

// tanh-form GELU: max |err| vs exact-erf gelu ~1e-3 (budget: 5e-2 abs)
__device__ __forceinline__ float gelu_f(float x) {
  float s = x * x;
  float g = x * (1.5957691216f + 0.0713548162f * s);
  float t = __expf(-g);
  return x * __builtin_amdgcn_rcpf(1.0f + t);
}

// ---------------- gating ----------------
__global__ __launch_bounds__(64) void gate_kernel(
    const float* __restrict__ x, const float* __restrict__ gw, const float* __restrict__ gb,
    int* __restrict__ topidx, float* __restrict__ topw, int* __restrict__ counts) {
  int t = blockIdx.x;
  int l = threadIdx.x;
  const float* xt = x + (size_t)t * H_DIM;
  float acc[E_NUM];
  #pragma unroll
  for (int e = 0; e < E_NUM; e++) acc[e] = 0.f;
  for (int k = l; k < H_DIM; k += 64) {
    float xv = xt[k];
    #pragma unroll
    for (int e = 0; e < E_NUM; e++) acc[e] += xv * gw[e * H_DIM + k];
  }
  #pragma unroll
  for (int e = 0; e < E_NUM; e++) {
    float v = acc[e];
    #pragma unroll
    for (int off = 32; off > 0; off >>= 1) v += __shfl_xor(v, off, 64);
    acc[e] = v;
  }
  if (l == 0) {
    float s[E_NUM];
    #pragma unroll
    for (int e = 0; e < E_NUM; e++) s[e] = 1.f / (1.f + __expf(-(acc[e] + gb[e])));
    int i1 = 0; float v1 = s[0];
    #pragma unroll
    for (int e = 1; e < E_NUM; e++) if (s[e] > v1) { v1 = s[e]; i1 = e; }
    int i2 = -1; float v2 = -1.f;
    #pragma unroll
    for (int e = 0; e < E_NUM; e++) if (e != i1 && s[e] > v2) { v2 = s[e]; i2 = e; }
    float denom = v1 + v2 + 1e-6f;
    topidx[t * 2]     = i1; topidx[t * 2 + 1] = i2;
    topw[t * 2]       = v1 / denom;
    topw[t * 2 + 1]   = v2 / denom;
    atomicAdd(&counts[i1], 1);
    atomicAdd(&counts[i2], 1);
  }
}

__global__ void init_kernel(int* counts) {
  if (threadIdx.x < E_NUM) counts[threadIdx.x] = 0;
}

// offsets + 128-row tile map over {8 routed experts + shared(e=8, cnt=T_TOK)}
__global__ void scan_kernel(const int* __restrict__ counts, int* __restrict__ offs,
                            int* __restrict__ cursor, int* __restrict__ tmE,
                            int* __restrict__ tmM, int* __restrict__ tmCnt) {
  if (threadIdx.x == 0) {
    int a = 0;
    for (int e = 0; e < E_NUM; e++) { offs[e] = a; a += counts[e]; cursor[e] = 0; }
    offs[E_NUM] = a;                 // == 8192
    offs[E_NUM + 1] = a + T_TOK;     // shared slots 8192..12287
    int c = 0;
    for (int e = 0; e <= E_NUM; e++) {
      int cnt = (e < E_NUM) ? counts[e] : T_TOK;
      for (int m0 = 0; m0 < cnt; m0 += 128) { tmE[c] = e; tmM[c] = m0; c++; }
    }
    tmCnt[0] = c;                    // <= MAX_MT
  }
}

__global__ void dispatch_kernel(const int* __restrict__ topidx, const float* __restrict__ topw,
                                const int* __restrict__ offs, int* __restrict__ cursor,
                                int* __restrict__ gidx, int* __restrict__ slot_of) {
  int t = blockIdx.x * blockDim.x + threadIdx.x;
  if (t >= T_TOK) return;
  #pragma unroll
  for (int j = 0; j < 2; j++) {
    int ex  = topidx[t * 2 + j];
    int pos = atomicAdd(&cursor[ex], 1);
    int slot = offs[ex] + pos;
    gidx[slot] = t;
    slot_of[t * 2 + j] = slot;
  }
  gidx[2 * T_TOK + t] = t;   // shared expert gathers token t
}

// ---------------- casts ----------------
__global__ __launch_bounds__(256) void cast_x_kernel(const float* __restrict__ x,
                                                     unsigned short* __restrict__ xb) {
  int i = blockIdx.x * blockDim.x + threadIdx.x;   // covers T*H/4
  float4 v = ((const float4*)x)[i];
  ushort4 o;
  o.x = f2bf(v.x); o.y = f2bf(v.y); o.z = f2bf(v.z); o.w = f2bf(v.w);
  ((ushort4*)xb)[i] = o;
}

// in: [z][R][C] f32  ->  out: [z][C][R] bf16 ; 64x64 tiles, float4 reads, ushort4 writes
__global__ __launch_bounds__(256) void transpose_cast_kernel(
    const float* __restrict__ in, unsigned short* __restrict__ out, int R, int C) {
  __shared__ float tile[64][65];
  const size_t bo = (size_t)blockIdx.z * (size_t)R * C;
  const float* inb = in + bo;
  unsigned short* outb = out + bo;
  int c0 = blockIdx.x * 64, r0 = blockIdx.y * 64;
  int tx = threadIdx.x & 15, ty = threadIdx.x >> 4;   // 16 x 16
  #pragma unroll
  for (int i = 0; i < 4; i++) {
    int row = ty + i * 16;
    float4 v = *(const float4*)(inb + (size_t)(r0 + row) * C + c0 + tx * 4);
    tile[row][tx * 4 + 0] = v.x;
    tile[row][tx * 4 + 1] = v.y;
    tile[row][tx * 4 + 2] = v.z;
    tile[row][tx * 4 + 3] = v.w;
  }
  __syncthreads();
  int rr0 = tx * 4;
  #pragma unroll
  for (int p = 0; p < 4; p++) {
    int col = p * 16 + ty;
    ushort4 o;
    o.x = f2bf(tile[rr0 + 0][col]);
    o.y = f2bf(tile[rr0 + 1][col]);
    o.z = f2bf(tile[rr0 + 2][col]);
    o.w = f2bf(tile[rr0 + 3][col]);
    *(ushort4*)(outb + (size_t)(c0 + col) * R + r0 + rr0) = o;
  }
}

// ---------------- GEMM 128x128, BK=64, 4 waves, m97-style 2-barrier loop ----
// LDS rows of 64 bf16 (128B = 8 x 16B units), XOR swizzle u' = u ^ (row&7),
// staged via global_load_lds (linear dest, pre-swizzled global source).
// B columns permuted within each 64-group: LDS row r (rr=r&63) holds weight col
// n0 + (r&64) + 4*(rr&15) + (rr>>4)  -> lane owns 4 adjacent cols -> coalesced stores.
// Grid: (N/128, MAX_MT); flattened balanced tile map, early-exit on y>=tmCnt.
template <bool FFN1>
__global__ __launch_bounds__(256) void gemm128(
    const unsigned short* __restrict__ A,    // FFN1: xb [T][1024]; else hdn [12288][4096]
    const unsigned short* __restrict__ Bt,   // wAll [9][N][K] (K-contig)
    const float* __restrict__ b_r,           // routed bias [8][N]
    const float* __restrict__ b_s,           // shared bias [N]
    void* __restrict__ outp,                 // FFN1: bf16 hdn; else f32 y
    const int* __restrict__ gidx,
    const int* __restrict__ offs,            // [10]
    const int* __restrict__ tmE, const int* __restrict__ tmM,
    const int* __restrict__ tmCnt,
    int K, int N) {
  if ((int)blockIdx.y >= tmCnt[0]) return;

  __shared__ __align__(16) char ldsA[128 * 128];
  __shared__ __align__(16) char ldsB[128 * 128];
  __shared__ int tokLds[128];

  const int tid = threadIdx.x;
  const int w = tid >> 6;
  const int l = tid & 63;
  const int e  = tmE[blockIdx.y];
  const int m0 = tmM[blockIdx.y];
  const int cnt = offs[e + 1] - offs[e];
  const int base = offs[e] + m0;
  const int valid = min(128, cnt - m0);
  const int n0 = blockIdx.x * 128;

  if (FFN1) {
    if (tid < 128) tokLds[tid] = gidx[base + min(tid, valid - 1)];
    __syncthreads();
  }

  // staging: 256 threads x (4 A + 4 B) x 16B per K-tile
  const int lr = l >> 3;             // row within 8-row staging group
  const int su = (l & 7) ^ lr;       // pre-swizzled source 16B-unit
  const unsigned short* aSrc[4];
  const unsigned short* bSrc[4];
  const unsigned short* BtE = Bt + (size_t)e * (size_t)N * (size_t)K;
  #pragma unroll
  for (int i = 0; i < 4; i++) {
    int r = w * 32 + i * 8 + lr;
    size_t arow = FFN1 ? (size_t)tokLds[r] : (size_t)(base + r);
    aSrc[i] = A + arow * (size_t)K + su * 8;
    int rr = r & 63;
    int nr = n0 + (r & 64) + ((rr & 15) << 2) + (rr >> 4);   // col permutation
    bSrc[i] = BtE + (size_t)nr * (size_t)K + su * 8;
  }
  char* aDst[4];
  char* bDst[4];
  #pragma unroll
  for (int i = 0; i < 4; i++) {
    aDst[i] = ldsA + (w * 32 + i * 8) * 128;
    bDst[i] = ldsB + (w * 32 + i * 8) * 128;
  }

  f32x4 acc[4][4];
  #pragma unroll
  for (int m = 0; m < 4; m++)
    #pragma unroll
    for (int n = 0; n < 4; n++) acc[m][n] = (f32x4){0.f, 0.f, 0.f, 0.f};

  const int wr = w >> 1, wc = w & 1;
  const int l15 = l & 15, l4 = l >> 4, l7 = l & 7;

  for (int kt = 0; kt < K; kt += 64) {
    #pragma unroll
    for (int i = 0; i < 4; i++)
      __builtin_amdgcn_global_load_lds((const AS1 void*)(aSrc[i] + kt),
                                       (AS3 void*)aDst[i], 16, 0, 0);
    #pragma unroll
    for (int i = 0; i < 4; i++)
      __builtin_amdgcn_global_load_lds((const AS1 void*)(bSrc[i] + kt),
                                       (AS3 void*)bDst[i], 16, 0, 0);
    __syncthreads();   // drains vmcnt before barrier
    #pragma unroll
    for (int kk = 0; kk < 2; kk++) {
      bf16x8 af[4], bfr[4];
      #pragma unroll
      for (int m = 0; m < 4; m++) {
        int r = wr * 64 + m * 16 + l15;
        af[m] = *(const bf16x8*)(ldsA + r * 128 + (((kk * 4 + l4) ^ l7) << 4));
      }
      #pragma unroll
      for (int n = 0; n < 4; n++) {
        int r = wc * 64 + n * 16 + l15;
        bfr[n] = *(const bf16x8*)(ldsB + r * 128 + (((kk * 4 + l4) ^ l7) << 4));
      }
      #pragma unroll
      for (int m = 0; m < 4; m++)
        #pragma unroll
        for (int n = 0; n < 4; n++)
          acc[m][n] = __builtin_amdgcn_mfma_f32_16x16x32_bf16(af[m], bfr[n], acc[m][n], 0, 0, 0);
    }
    __syncthreads();
  }

  // epilogue: lane owns cols c0..c0+3 (B-permutation); C/D row = l4*4+j
  const float* bias = (e < E_NUM) ? (b_r + (size_t)e * N) : b_s;
  const int c0 = n0 + wc * 64 + 4 * l15;
  float4 bv = *(const float4*)(bias + c0);
  if (FFN1) {
    unsigned short* hdn = (unsigned short*)outp;
    #pragma unroll
    for (int m = 0; m < 4; m++) {
      #pragma unroll
      for (int j = 0; j < 4; j++) {
        int rl = wr * 64 + m * 16 + l4 * 4 + j;
        if (rl < valid) {
          ushort4 o;
          o.x = f2bf(gelu_f(acc[m][0][j] + bv.x));
          o.y = f2bf(gelu_f(acc[m][1][j] + bv.y));
          o.z = f2bf(gelu_f(acc[m][2][j] + bv.z));
          o.w = f2bf(gelu_f(acc[m][3][j] + bv.w));
          *(ushort4*)(hdn + (size_t)(base + rl) * N + c0) = o;
        }
      }
    }
  } else {
    float* y = (float*)outp;
    #pragma unroll
    for (int m = 0; m < 4; m++) {
      #pragma unroll
      for (int j = 0; j < 4; j++) {
        int rl = wr * 64 + m * 16 + l4 * 4 + j;
        if (rl < valid) {
          float4 o;
          o.x = acc[m][0][j] + bv.x;
          o.y = acc[m][1][j] + bv.y;
          o.z = acc[m][2][j] + bv.z;
          o.w = acc[m][3][j] + bv.w;
          *(float4*)(y + (size_t)(base + rl) * N + c0) = o;
        }
      }
    }
  }
}

// out[t] = w1*y[s1] + w2*y[s2] + 0.1*y[8192+t]   (biases already in y)
__global__ __launch_bounds__(256) void combine_kernel(
    const float* __restrict__ y, const float* __restrict__ topw,
    const int* __restrict__ slot_of, float* __restrict__ out) {
  int t = blockIdx.x;
  int g = threadIdx.x;
  int s1 = slot_of[2 * t], s2 = slot_of[2 * t + 1];
  float w1 = topw[2 * t], w2 = topw[2 * t + 1];
  float4 a = *(const float4*)(y + (size_t)s1 * H_DIM + g * 4);
  float4 b = *(const float4*)(y + (size_t)s2 * H_DIM + g * 4);
  float4 c = *(const float4*)(y + (size_t)(2 * T_TOK + t) * H_DIM + g * 4);
  float4 o;
  o.x = w1 * a.x + w2 * b.x + 0.1f * c.x;
  o.y = w1 * a.y + w2 * b.y + 0.1f * c.y;
  o.z = w1 * a.z + w2 * b.z + 0.1f * c.z;
  o.w = w1 * a.w + w2 * b.w + 0.1f * c.w;
  *(float4*)(out + (size_t)t * H_DIM + g * 4) = o;
}

// ---------------- host ----------------
extern "C" void kernel_launch(void* const* d_in, const int* in_sizes, int n_in,
                              void* d_out, int out_size, void* d_ws, size_t ws_size,
                              hipStream_t stream) {
  const float* x   = (const float*)d_in[0];
  const float* gw  = (const float*)d_in[1];
  const float* gb  = (const float*)d_in[2];
  const float* w1  = (const float*)d_in[3];
  const float* b1  = (const float*)d_in[4];
  const float* w2  = (const float*)d_in[5];
  const float* b2  = (const float*)d_in[6];
  const float* sw1 = (const float*)d_in[7];
  const float* sb1 = (const float*)d_in[8];
  const float* sw2 = (const float*)d_in[9];
  const float* sb2 = (const float*)d_in[10];
  float* out = (float*)d_out;

  char* p = (char*)d_ws;
  auto alloc = [&](size_t bytes) {
    char* r = p;
    p += (bytes + 255) & ~(size_t)255;
    return r;
  };
  int*   counts  = (int*)alloc(E_NUM * 4);
  int*   cursor  = (int*)alloc(E_NUM * 4);
  int*   offs    = (int*)alloc((E_NUM + 2) * 4);
  int*   topidx  = (int*)alloc((size_t)T_TOK * 2 * 4);
  float* topw    = (float*)alloc((size_t)T_TOK * 2 * 4);
  int*   slot_of = (int*)alloc((size_t)T_TOK * 2 * 4);
  int*   gidx    = (int*)alloc((size_t)3 * T_TOK * 4);
  int*   tmE     = (int*)alloc(MAX_MT * 4);
  int*   tmM     = (int*)alloc(MAX_MT * 4);
  int*   tmCnt   = (int*)alloc(4);
  unsigned short* xb   = (unsigned short*)alloc((size_t)T_TOK * H_DIM * 2);
  unsigned short* wAll = (unsigned short*)alloc((size_t)(E_NUM + 1) * FF_DIM * H_DIM * 2);
  unsigned short* hdn  = (unsigned short*)alloc((size_t)3 * T_TOK * FF_DIM * 2);   // 12288 x 4096 bf16
  float*          yb   = (float*)alloc((size_t)3 * T_TOK * H_DIM * 4);             // 12288 x 1024 f32

  // routing
  init_kernel<<<1, 64, 0, stream>>>(counts);
  gate_kernel<<<T_TOK, 64, 0, stream>>>(x, gw, gb, topidx, topw, counts);
  scan_kernel<<<1, 1, 0, stream>>>(counts, offs, cursor, tmE, tmM, tmCnt);
  dispatch_kernel<<<T_TOK / 256, 256, 0, stream>>>(topidx, topw, offs, cursor, gidx, slot_of);

  // x -> bf16
  cast_x_kernel<<<(T_TOK * H_DIM / 4) / 256, 256, 0, stream>>>(x, xb);

  // FFN1 weights -> bf16 [N][K]; shared expert = expert 8
  transpose_cast_kernel<<<dim3(FF_DIM / 64, H_DIM / 64, E_NUM), 256, 0, stream>>>(w1, wAll, H_DIM, FF_DIM);
  transpose_cast_kernel<<<dim3(FF_DIM / 64, H_DIM / 64, 1), 256, 0, stream>>>(
      sw1, wAll + (size_t)E_NUM * FF_DIM * H_DIM, H_DIM, FF_DIM);
  gemm128<true><<<dim3(FF_DIM / 128, MAX_MT), 256, 0, stream>>>(
      xb, wAll, b1, sb1, hdn, gidx, offs, tmE, tmM, tmCnt, H_DIM, FF_DIM);

  // FFN2 weights (reuse wAll) -> bf16 [N][K]
  transpose_cast_kernel<<<dim3(H_DIM / 64, FF_DIM / 64, E_NUM), 256, 0, stream>>>(w2, wAll, FF_DIM, H_DIM);
  transpose_cast_kernel<<<dim3(H_DIM / 64, FF_DIM / 64, 1), 256, 0, stream>>>(
      sw2, wAll + (size_t)E_NUM * FF_DIM * H_DIM, FF_DIM, H_DIM);
  gemm128<false><<<dim3(H_DIM / 128, MAX_MT), 256, 0, stream>>>(
      hdn, wAll, b2, sb2, yb, gidx, offs, tmE, tmM, tmCnt, FF_DIM, H_DIM);

  // weighted combine (routed top-2 + 0.1 * shared)
  combine_kernel<<<T_TOK, 256, 0, stream>>>(yb, topw, slot_of, out);
}